// Round 2
// baseline (849.132 us; speedup 1.0000x reference)
//
#include <hip/hip_runtime.h>
#include <hip/hip_fp16.h>

#define DD 1024
#define LL 128
#define NSEG 64
#define RPB 128          // rows per block
#define SUB 32           // rows per sub-tile (pipeline stage)
#define NT (RPB / SUB)   // 4 pipeline iterations

typedef _Float16 half8  __attribute__((ext_vector_type(8)));
typedef _Float16 half4v __attribute__((ext_vector_type(4)));
typedef float    floatx4 __attribute__((ext_vector_type(4)));
typedef float    f4v     __attribute__((ext_vector_type(4)));

// ---------------- prep: convert Wa|Wb -> f16 Wab [256][1024], zero seg buffers ----
__global__ __launch_bounds__(256)
void prep_kernel(const float* __restrict__ Wa, const float* __restrict__ Wb,
                 _Float16* __restrict__ Wab, unsigned* __restrict__ smaxu,
                 float* __restrict__ denom)
{
    int gid = blockIdx.x * 256 + threadIdx.x;
    if (gid < LL * DD)            Wab[gid] = (_Float16)Wa[gid];
    else if (gid < 2 * LL * DD)   Wab[gid] = (_Float16)Wb[gid - LL * DD];
    if (gid < NSEG)               smaxu[gid] = 0u;
    else if (gid < 2 * NSEG)      denom[gid - NSEG] = 0.0f;
}

// ---- fused: normalize + dual GEMM + gate + Wc dot -> raw scores (pipelined) ----
__global__ __launch_bounds__(256, 2)
void fused_main(const float* __restrict__ feat,
                const _Float16* __restrict__ Wab,
                const float* __restrict__ ba,
                const float* __restrict__ bb,
                const float* __restrict__ Wc,
                const float* __restrict__ bc,
                float* __restrict__ out_norm,
                float* __restrict__ score_raw)
{
    __shared__ __align__(16) char tile[SUB * 2048];   // 32 rows x 1024 f16, swizzled (64 KB)
    __shared__ float scorebuf[RPB];

    const int tid  = threadIdx.x;
    const int wave = tid >> 6;
    const int lane = tid & 63;
    const int llo  = lane & 15;
    const int lhi  = lane >> 4;
    const long long blockRow0 = (long long)blockIdx.x * RPB;

    if (tid < RPB) scorebuf[tid] = 0.0f;

    float4 P[8][4];   // prefetch registers: 8 rows x 4 float4 per thread (128 VGPR)

    // issue global loads for sub-tile t into P (fire and forget)
    auto issue = [&](int t) {
        const long long r0 = blockRow0 + (long long)t * SUB + wave * 8;
        const float4* src = reinterpret_cast<const float4*>(feat) + r0 * (DD / 4) + lane;
        #pragma unroll
        for (int j = 0; j < 8; ++j) {
            const float4* s = src + (long long)j * (DD / 4);
            #pragma unroll
            for (int c = 0; c < 4; ++c) P[j][c] = s[c * 64];
        }
    };

    // consume P: row norms, out_norm stores, f16 convert + swizzled LDS stage
    auto process = [&](int t) {
        const long long r0 = blockRow0 + (long long)t * SUB + wave * 8;
        #pragma unroll
        for (int j = 0; j < 8; ++j) {
            float ss = 0.0f;
            #pragma unroll
            for (int c = 0; c < 4; ++c)
                ss += P[j][c].x * P[j][c].x + P[j][c].y * P[j][c].y
                    + P[j][c].z * P[j][c].z + P[j][c].w * P[j][c].w;
            #pragma unroll
            for (int off = 32; off >= 1; off >>= 1) ss += __shfl_xor(ss, off);
            const float rinv = 1.0f / fmaxf(sqrtf(ss), 1e-12f);

            f4v* dst = reinterpret_cast<f4v*>(out_norm) + (r0 + j) * (DD / 4) + lane;
            #pragma unroll
            for (int c = 0; c < 4; ++c) {
                f4v v;
                v[0] = P[j][c].x * rinv; v[1] = P[j][c].y * rinv;
                v[2] = P[j][c].z * rinv; v[3] = P[j][c].w * rinv;
                __builtin_nontemporal_store(v, &dst[c * 64]);
            }
            const int lrow = wave * 8 + j;
            const int swz = (lrow & 7) << 4;
            #pragma unroll
            for (int c = 0; c < 4; ++c) {
                half4v h;
                h[0] = (_Float16)P[j][c].x; h[1] = (_Float16)P[j][c].y;
                h[2] = (_Float16)P[j][c].z; h[3] = (_Float16)P[j][c].w;
                *reinterpret_cast<half4v*>(tile + lrow * 2048 + ((c * 512 + lane * 8) ^ swz)) = h;
            }
        }
    };

    // MFMA over the staged 32-row tile + gated epilogue into scorebuf[t*32 ..]
    auto mfma_phase = [&](int t) {
        floatx4 acc_a[2][2];
        floatx4 acc_b[2][2];
        #pragma unroll
        for (int rt = 0; rt < 2; ++rt)
            #pragma unroll
            for (int ct = 0; ct < 2; ++ct) { acc_a[rt][ct] = (floatx4)0.0f; acc_b[rt][ct] = (floatx4)0.0f; }

        const int colA0 = wave * 32 + llo;

        #pragma unroll 2
        for (int ks = 0; ks < 32; ++ks) {
            half8 af[2];
            #pragma unroll
            for (int rt = 0; rt < 2; ++rt) {
                const int lrow = rt * 16 + llo;
                const int boff = lrow * 2048 + ((ks * 64 + lhi * 16) ^ ((lrow & 7) << 4));
                af[rt] = *reinterpret_cast<const half8*>(tile + boff);
            }
            half8 bfa[2], bfb[2];
            #pragma unroll
            for (int ct = 0; ct < 2; ++ct) {
                bfa[ct] = *reinterpret_cast<const half8*>(Wab + (size_t)(colA0 + ct * 16) * DD + ks * 32 + lhi * 8);
                bfb[ct] = *reinterpret_cast<const half8*>(Wab + (size_t)(LL + colA0 + ct * 16) * DD + ks * 32 + lhi * 8);
            }
            #pragma unroll
            for (int rt = 0; rt < 2; ++rt)
                #pragma unroll
                for (int ct = 0; ct < 2; ++ct) {
                    acc_a[rt][ct] = __builtin_amdgcn_mfma_f32_16x16x32_f16(af[rt], bfa[ct], acc_a[rt][ct], 0, 0, 0);
                    acc_b[rt][ct] = __builtin_amdgcn_mfma_f32_16x16x32_f16(af[rt], bfb[ct], acc_b[rt][ct], 0, 0, 0);
                }
        }

        float wcv[2], bav[2], bbv[2];
        #pragma unroll
        for (int ct = 0; ct < 2; ++ct) {
            const int c = colA0 + ct * 16;
            wcv[ct] = Wc[c]; bav[ct] = ba[c]; bbv[ct] = bb[c];
        }
        #pragma unroll
        for (int rt = 0; rt < 2; ++rt) {
            float s[4] = {0.f, 0.f, 0.f, 0.f};
            #pragma unroll
            for (int ct = 0; ct < 2; ++ct)
                #pragma unroll
                for (int j = 0; j < 4; ++j) {
                    const float av = 1.0f / (1.0f + expf(-(acc_a[rt][ct][j] + bav[ct])));
                    const float bv = tanhf(acc_b[rt][ct][j] + bbv[ct]);
                    s[j] += av * bv * wcv[ct];
                }
            #pragma unroll
            for (int j = 0; j < 4; ++j) {
                s[j] += __shfl_xor(s[j], 1);
                s[j] += __shfl_xor(s[j], 2);
                s[j] += __shfl_xor(s[j], 4);
                s[j] += __shfl_xor(s[j], 8);
            }
            if (llo == 0) {
                #pragma unroll
                for (int j = 0; j < 4; ++j)
                    atomicAdd(&scorebuf[t * SUB + rt * 16 + lhi * 4 + j], s[j]);
            }
        }
    };

    // ---------------- software pipeline ----------------
    issue(0);
    process(0);
    for (int t = 0; t < NT; ++t) {
        __syncthreads();                 // tile(t) staged & visible
        if (t + 1 < NT) issue(t + 1);    // HBM reads in flight under MFMA phase
        mfma_phase(t);
        __syncthreads();                 // all reads of tile(t) done
        if (t + 1 < NT) process(t + 1);  // overwrite tile with sub-tile t+1
    }
    if (tid < RPB) score_raw[blockRow0 + tid] = scorebuf[tid] + bc[0];
}

// ---------------- segment softmax (3 tiny passes over N floats) ----------------
__global__ __launch_bounds__(256)
void seg_max_kernel(const float* __restrict__ score, const int* __restrict__ batch,
                    unsigned* __restrict__ smaxu, int n)
{
    __shared__ unsigned sm[NSEG];
    const int t = threadIdx.x;
    if (t < NSEG) sm[t] = 0u;
    __syncthreads();
    const int stride = gridDim.x * blockDim.x;
    for (int i = blockIdx.x * blockDim.x + t; i < n; i += stride) {
        const unsigned b = __float_as_uint(score[i]);
        const unsigned m = (b & 0x80000000u) ? ~b : (b | 0x80000000u);
        atomicMax(&sm[batch[i]], m);
    }
    __syncthreads();
    if (t < NSEG) atomicMax(&smaxu[t], sm[t]);
}

__global__ __launch_bounds__(256)
void seg_exp_kernel(float* __restrict__ score_inout, const int* __restrict__ batch,
                    const unsigned* __restrict__ smaxu, float* __restrict__ denom, int n)
{
    __shared__ float sd[NSEG];
    __shared__ float smx[NSEG];
    const int t = threadIdx.x;
    if (t < NSEG) {
        sd[t] = 0.0f;
        const unsigned u = smaxu[t];
        const unsigned b = (u & 0x80000000u) ? (u ^ 0x80000000u) : ~u;
        smx[t] = __uint_as_float(b);
    }
    __syncthreads();
    const int stride = gridDim.x * blockDim.x;
    for (int i = blockIdx.x * blockDim.x + t; i < n; i += stride) {
        const int b = batch[i];
        const float e = expf(score_inout[i] - smx[b]);
        score_inout[i] = e;
        atomicAdd(&sd[b], e);
    }
    __syncthreads();
    if (t < NSEG) atomicAdd(&denom[t], sd[t]);
}

__global__ __launch_bounds__(256)
void seg_div_kernel(float* __restrict__ score_inout, const int* __restrict__ batch,
                    const float* __restrict__ denom, int n)
{
    const int stride = gridDim.x * blockDim.x;
    for (int i = blockIdx.x * blockDim.x + threadIdx.x; i < n; i += stride)
        score_inout[i] = score_inout[i] / (denom[batch[i]] + 1e-16f);
}

// ---------------------------------------------------------------------------
extern "C" void kernel_launch(void* const* d_in, const int* in_sizes, int n_in,
                              void* d_out, int out_size, void* d_ws, size_t ws_size,
                              hipStream_t stream)
{
    const float* feat  = (const float*)d_in[0];
    const int*   batch = (const int*)d_in[1];
    // d_in[2] = istrain (unused; dropout is identity at eval)
    const float* Wa = (const float*)d_in[3];
    const float* ba = (const float*)d_in[4];
    const float* Wb = (const float*)d_in[5];
    const float* bb = (const float*)d_in[6];
    const float* Wc = (const float*)d_in[7];
    const float* bc = (const float*)d_in[8];

    const int N = in_sizes[1];                 // 262144

    float* out_norm  = (float*)d_out;
    float* out_score = (float*)d_out + (size_t)N * DD;

    char* ws = (char*)d_ws;
    _Float16* Wab   = (_Float16*)ws;                         // 512 KB
    unsigned* smaxu = (unsigned*)(ws + 2 * LL * DD * 2);     // 64 u32
    float*    denom = (float*)(ws + 2 * LL * DD * 2 + 256);  // 64 f32

    prep_kernel<<<(2 * LL * DD + 255) / 256, 256, 0, stream>>>(Wa, Wb, Wab, smaxu, denom);
    fused_main<<<N / RPB, 256, 0, stream>>>(feat, Wab, ba, bb, Wc, bc, out_norm, out_score);
    seg_max_kernel<<<512, 256, 0, stream>>>(out_score, batch, smaxu, N);
    seg_exp_kernel<<<512, 256, 0, stream>>>(out_score, batch, smaxu, denom, N);
    seg_div_kernel<<<512, 256, 0, stream>>>(out_score, batch, denom, N);
}